// Round 3
// baseline (330.661 us; speedup 1.0000x reference)
//
#include <hip/hip_runtime.h>

// PointSample: bilinear grid_sample, align_corners=False, border clamp.
// features: [B=8, H=256, W=256, C=128] fp32 channels-last
// grid:     [B=8, P=8192, 2] fp32 (x, y) in [0, 1]
// out:      [B, P, C] fp32
//
// R3 (= R2 with compile fix): 2 points per thread (8 independent corner
// gathers in flight), nontemporal output stores via clang ext_vector_type
// (HIP float4 class is rejected by __builtin_nontemporal_store), 32-bit
// offset addressing from a per-batch base pointer.
// 32 consecutive lanes cover one point's 128 channels as float4 -> each
// corner gather is a coalesced 512 B contiguous read; (x0,x1) corner pairs
// form 1 KiB runs at the memory controller.

typedef float vfloat4 __attribute__((ext_vector_type(4)));

constexpr int B = 8, H = 256, W = 256, C = 128, P = 8192;
constexpr int C4 = C / 4;             // 32 float4 chunks per point
constexpr int PTS_PER_BLOCK = 16;     // 256 threads / 32 lanes-per-point * 2

__global__ __launch_bounds__(256) void pointsample_kernel(
    const vfloat4* __restrict__ feat,   // [B*H*W*C4]
    const float2* __restrict__ grid,    // [B*P] (x,y)
    vfloat4* __restrict__ out)          // [B*P*C4]
{
    const int tid = threadIdx.x;
    const int c4  = tid & (C4 - 1);          // channel-quad 0..31
    const int lp  = tid >> 5;                // 0..7
    const int p0  = blockIdx.x * PTS_PER_BLOCK + lp;  // first point
    const int p1  = p0 + 8;                  // second point (same batch: 8192%16==0)
    const int b   = p0 >> 13;                // batch index

    const float2 g0 = grid[p0];
    const float2 g1 = grid[p1];

    // ---- address math for both points (expression order mirrors reference)
    float x, y, ix, iy, x0f, y0f;
    int xi, yi;

    x = g0.x * 2.0f - 1.0f;  y = g0.y * 2.0f - 1.0f;
    ix = ((x + 1.0f) * (float)W - 1.0f) * 0.5f;
    iy = ((y + 1.0f) * (float)H - 1.0f) * 0.5f;
    x0f = floorf(ix);  y0f = floorf(iy);
    const float wxA = ix - x0f, wyA = iy - y0f;
    xi = (int)x0f;  yi = (int)y0f;
    const int ax0 = min(max(xi,     0), W - 1);
    const int ax1 = min(max(xi + 1, 0), W - 1);
    const int ay0 = min(max(yi,     0), H - 1);
    const int ay1 = min(max(yi + 1, 0), H - 1);

    x = g1.x * 2.0f - 1.0f;  y = g1.y * 2.0f - 1.0f;
    ix = ((x + 1.0f) * (float)W - 1.0f) * 0.5f;
    iy = ((y + 1.0f) * (float)H - 1.0f) * 0.5f;
    x0f = floorf(ix);  y0f = floorf(iy);
    const float wxB = ix - x0f, wyB = iy - y0f;
    xi = (int)x0f;  yi = (int)y0f;
    const int bx0 = min(max(xi,     0), W - 1);
    const int bx1 = min(max(xi + 1, 0), W - 1);
    const int by0 = min(max(yi,     0), H - 1);
    const int by1 = min(max(yi + 1, 0), H - 1);

    // ---- 8 independent corner gathers, all issued before any use
    const vfloat4* fb = feat + (size_t)b * (H * W * C4);
    const int r0a = ay0 * (W * C4), r1a = ay1 * (W * C4);
    const int r0b = by0 * (W * C4), r1b = by1 * (W * C4);

    const vfloat4 a00 = fb[r0a + ax0 * C4 + c4];
    const vfloat4 a01 = fb[r0a + ax1 * C4 + c4];
    const vfloat4 a10 = fb[r1a + ax0 * C4 + c4];
    const vfloat4 a11 = fb[r1a + ax1 * C4 + c4];
    const vfloat4 b00 = fb[r0b + bx0 * C4 + c4];
    const vfloat4 b01 = fb[r0b + bx1 * C4 + c4];
    const vfloat4 b10 = fb[r1b + bx0 * C4 + c4];
    const vfloat4 b11 = fb[r1b + bx1 * C4 + c4];

    // ---- blend point A
    {
        const float w00 = (1.0f - wyA) * (1.0f - wxA);
        const float w01 = (1.0f - wyA) * wxA;
        const float w10 = wyA * (1.0f - wxA);
        const float w11 = wyA * wxA;
        vfloat4 o = a00 * w00 + a01 * w01 + a10 * w10 + a11 * w11;
        __builtin_nontemporal_store(o, out + (size_t)p0 * C4 + c4);
    }
    // ---- blend point B
    {
        const float w00 = (1.0f - wyB) * (1.0f - wxB);
        const float w01 = (1.0f - wyB) * wxB;
        const float w10 = wyB * (1.0f - wxB);
        const float w11 = wyB * wxB;
        vfloat4 o = b00 * w00 + b01 * w01 + b10 * w10 + b11 * w11;
        __builtin_nontemporal_store(o, out + (size_t)p1 * C4 + c4);
    }
}

extern "C" void kernel_launch(void* const* d_in, const int* in_sizes, int n_in,
                              void* d_out, int out_size, void* d_ws, size_t ws_size,
                              hipStream_t stream) {
    const vfloat4* feat = (const vfloat4*)d_in[0];
    const float2*  grd  = (const float2*)d_in[1];
    vfloat4*       out  = (vfloat4*)d_out;

    constexpr int nblocks = B * P / PTS_PER_BLOCK;  // 4096
    pointsample_kernel<<<nblocks, 256, 0, stream>>>(feat, grd, out);
}